// Round 13
// baseline (170.790 us; speedup 1.0000x reference)
//
#include <hip/hip_runtime.h>
#include <hip/hip_bf16.h>
#include <math.h>

#define TT 2048
#define CC 1024
#define C3 3072
#define MM 8192   // B*T

typedef __attribute__((ext_vector_type(8))) short short8;
typedef __attribute__((ext_vector_type(4))) float f32x4;

__device__ __forceinline__ short bf16b(float x) {
  __hip_bfloat16 h = __float2bfloat16(x);
  return *reinterpret_cast<short*>(&h);
}

__device__ __forceinline__ unsigned cvtpk(float lo, float hi) {
  unsigned r;
  asm("v_cvt_pk_bf16_f32 %0, %1, %2" : "=v"(r) : "v"(lo), "v"(hi));
  return r;
}

__device__ __forceinline__ float exp2a(float x) {
  float r;
  asm("v_exp_f32 %0, %1" : "=v"(r) : "v"(x));
  return r;
}

__device__ __forceinline__ void gload16(const void* g, void* l) {
  __builtin_amdgcn_global_load_lds(
      (const __attribute__((address_space(1))) unsigned int*)g,
      (__attribute__((address_space(3))) unsigned int*)l, 16, 0, 0);
}

// ---------------------------------------------------------------------------
// Fused prep: [0,4096) x->bf16; [4096,7168) W_attn^T (Q cols scaled);
// [7168,8192) W_proj^T; [8192,8224) amask->bitmask.  One launch, 4 jobs.
// ---------------------------------------------------------------------------
__device__ __forceinline__ void cvt_t_body(const float* __restrict__ in,
                                           short* __restrict__ out, int R, int Cc,
                                           int c0, int r0, int limit, float scale,
                                           float (*t)[33], int tid) {
  const int tx = tid & 31, ty = tid >> 5;
#pragma unroll
  for (int i = 0; i < 4; ++i)
    t[ty + i * 8][tx] = in[(size_t)(r0 + ty + i * 8) * Cc + c0 + tx];
  __syncthreads();
#pragma unroll
  for (int i = 0; i < 4; ++i) {
    const int orow = c0 + ty + i * 8;
    const float f = (orow < limit) ? scale : 1.f;
    out[(size_t)orow * R + r0 + tx] = bf16b(t[tx][ty + i * 8] * f);
  }
}

__global__ __launch_bounds__(256) void prep(const float* __restrict__ x,
                                            short* __restrict__ xb,
                                            const float* __restrict__ Wa,
                                            short* __restrict__ Wta,
                                            const float* __restrict__ Wp,
                                            short* __restrict__ Wtp,
                                            const int* __restrict__ amask,
                                            unsigned long long* __restrict__ kmask,
                                            float scaleQ) {
  __shared__ float t[32][33];
  const int bid = blockIdx.x, tid = threadIdx.x;
  if (bid < 4096) {
    const int i = (bid * 256 + tid) * 8;
    float4 a = *reinterpret_cast<const float4*>(x + i);
    float4 b = *reinterpret_cast<const float4*>(x + i + 4);
    short8 r;
    r[0] = bf16b(a.x); r[1] = bf16b(a.y); r[2] = bf16b(a.z); r[3] = bf16b(a.w);
    r[4] = bf16b(b.x); r[5] = bf16b(b.y); r[6] = bf16b(b.z); r[7] = bf16b(b.w);
    *reinterpret_cast<short8*>(xb + i) = r;
  } else if (bid < 7168) {
    const int lb = bid - 4096;
    cvt_t_body(Wa, Wta, CC, C3, (lb % 96) * 32, (lb / 96) * 32, CC, scaleQ, t, tid);
  } else if (bid < 8192) {
    const int lb = bid - 7168;
    cvt_t_body(Wp, Wtp, CC, CC, (lb & 31) * 32, (lb >> 5) * 32, 0, 1.f, t, tid);
  } else {
    const int gw = (bid - 8192) * 4 + (tid >> 6);
    unsigned long long bits = __ballot(amask[gw * 64 + (tid & 63)] != 0);
    if ((tid & 63) == 0) kmask[gw] = bits;
  }
}

// ---------------------------------------------------------------------------
// bf16 MFMA GEMM: C[M,N] = A[M,K] * Bt[N,K]^T.  128x128 tile, BK=64 (128B
// LDS rows, slot^=(row&7) swizzle: measured 0 bank conflicts), 256 threads =
// 4 waves (2x2), 4x4 16x16 frags/wave, 32 MFMA/iter.  2-deep counted-vmcnt
// pipeline (2 x 32KB bufs).  Natural block order (bx%8 XCD striping).
// MODE 0: fp32 out.  MODE 2 (qkv): cols<2048 -> bf16 qkv; cols>=2048 (V) ->
// LDS-transpose epilogue -> key-permuted vT[bh*64+d][t] (packed b64 writes).
// ---------------------------------------------------------------------------
template <int MODE>
__global__ __launch_bounds__(256) void gemm_bt(const short* __restrict__ A,
                                               const short* __restrict__ Bt,
                                               void* __restrict__ Cout,
                                               short* __restrict__ vT,
                                               int M, int N, int K) {
  __shared__ __align__(16) char Ls[2 * 32768];   // [buf][A 16KB | B 16KB]
  const int tid = threadIdx.x, lane = tid & 63, w = tid >> 6;
  const int g = lane >> 4, cw = lane & 15;
  const int m0 = blockIdx.y * 128, n0 = blockIdx.x * 128;
  const int wr = (w >> 1) * 64, wc = (w & 1) * 64;

  f32x4 acc[4][4];
#pragma unroll
  for (int i = 0; i < 4; ++i)
#pragma unroll
    for (int j = 0; j < 4; ++j) acc[i][j] = (f32x4){0.f, 0.f, 0.f, 0.f};

  // staging: row r = u*32 + (tid>>3), physical 16B slot tid&7 holds
  // logical k-group (tid&7) ^ (r&7)  (pre-swizzled source)
  const int sr = tid >> 3;                              // 0..31 (+u*32)
  const int sc = ((tid & 7) ^ (sr & 7)) << 3;           // source k elements
  const short* Asrc = A + (size_t)(m0 + sr) * K + sc;
  const short* Bsrc = Bt + (size_t)(n0 + sr) * K + sc;
  const size_t ustep = (size_t)32 * K;

  const int nt = K >> 6;   // BK=64; assumes nt >= 2

#define STAGE(kt, buf)                                                        \
  {                                                                           \
    char* dst_ = Ls + (buf) * 32768;                                          \
    const int k0_ = (kt) * 64;                                                \
    _Pragma("unroll")                                                         \
    for (int u = 0; u < 4; ++u)                                               \
      gload16(Asrc + u * ustep + k0_, dst_ + u * 4096 + tid * 16);            \
    _Pragma("unroll")                                                         \
    for (int u = 0; u < 4; ++u)                                               \
      gload16(Bsrc + u * ustep + k0_, dst_ + 16384 + u * 4096 + tid * 16);    \
  }

  STAGE(0, 0);
  STAGE(1, 1);

  const int xorm = (cw & 7) << 4;   // frag rows have row&7 == cw&7

#pragma unroll 1
  for (int t = 0; t < nt; ++t) {
    if (t + 1 < nt) {
      asm volatile("s_waitcnt vmcnt(8)" ::: "memory");
    } else {
      asm volatile("s_waitcnt vmcnt(0)" ::: "memory");
    }
    asm volatile("s_barrier" ::: "memory");

    const char* LA = Ls + (t & 1) * 32768;
    const char* LB = LA + 16384;

#pragma unroll
    for (int ks = 0; ks < 2; ++ks) {
      const int xo = (ks * 64 + g * 16) ^ xorm;
      short8 af[4], bf[4];
#pragma unroll
      for (int mt = 0; mt < 4; ++mt)
        af[mt] = *reinterpret_cast<const short8*>(LA + (wr + mt * 16 + cw) * 128 + xo);
#pragma unroll
      for (int ntn = 0; ntn < 4; ++ntn)
        bf[ntn] = *reinterpret_cast<const short8*>(LB + (wc + ntn * 16 + cw) * 128 + xo);
      __builtin_amdgcn_s_setprio(1);
#pragma unroll
      for (int mt = 0; mt < 4; ++mt)
#pragma unroll
        for (int ntn = 0; ntn < 4; ++ntn)
          acc[mt][ntn] = __builtin_amdgcn_mfma_f32_16x16x32_bf16(af[mt], bf[ntn], acc[mt][ntn], 0, 0, 0);
      __builtin_amdgcn_s_setprio(0);
    }

    asm volatile("s_barrier" ::: "memory");
    if (t + 2 < nt) STAGE(t + 2, t & 1);
  }
#undef STAGE

  if (MODE == 2 && n0 >= 2048) {
    // ---- fused V epilogue: acc -> LDS [d][t] (key-permuted, swizzled) ----
    char* Lt = Ls;   // 128 rows x 256B = 32KB
#pragma unroll
    for (int mt = 0; mt < 4; ++mt)
#pragma unroll
      for (int ntn = 0; ntn < 4; ++ntn) {
        const int dl = wc + ntn * 16 + cw;          // local d 0..127
        const int xm = (dl & 15) << 4;
        const int tl0 = wr + mt * 16 + g * 4;       // low 2 bits zero
        const int l5 = tl0 & 31;
        const int tp0 = (tl0 & ~31) | ((l5 & 8) << 1) | ((l5 & 4) << 1) |
                        ((l5 & 16) >> 2);           // + j passes through
        uint2 v;
        v.x = cvtpk(acc[mt][ntn][0], acc[mt][ntn][1]);
        v.y = cvtpk(acc[mt][ntn][2], acc[mt][ntn][3]);
        *reinterpret_cast<uint2*>(Lt + dl * 256 + ((tp0 * 2) ^ xm)) = v;
      }
    __syncthreads();
    // ---- coalesced write: lane pair covers one vT row (256B) ----
    const int dl = tid >> 1, hf = tid & 1;
    const int b = m0 >> 11, t0 = m0 & 2047;
    const int h = ((n0 - 2048) >> 6) + (dl >> 6);
    const int d = dl & 63;
    short* dst = vT + (size_t)((b * 16 + h) * 64 + d) * TT + t0 + hf * 64;
#pragma unroll
    for (int c = 0; c < 8; ++c) {
      const int ca = hf * 8 + c;
      const int slot = ca ^ (dl & 15);
      *reinterpret_cast<short8*>(dst + c * 8) =
          *reinterpret_cast<const short8*>(Lt + dl * 256 + slot * 16);
    }
    return;
  }

#pragma unroll
  for (int mt = 0; mt < 4; ++mt)
#pragma unroll
    for (int ntn = 0; ntn < 4; ++ntn)
#pragma unroll
      for (int j = 0; j < 4; ++j) {
        int row = m0 + wr + mt * 16 + g * 4 + j;
        int col = n0 + wc + ntn * 16 + cw;
        if (MODE == 2)
          ((short*)Cout)[(size_t)row * N + col] = bf16b(acc[mt][ntn][j]);
        else
          ((float*)Cout)[(size_t)row * N + col] = acc[mt][ntn][j];
      }
}

// ---------------------------------------------------------------------------
// Flash attention, swapped-operand MFMA.  Block = 4 waves (256 thr); wave
// owns 16 q rows; ONE q-tile (64 rows) per block -> 2048 blocks, qt
// descending with block-ID (long blocks first).  Single-buffered KV staging
// (16.6 KB LDS) -> 8 blocks/CU = 32 waves/CU: the per-tile staging drain is
// hidden by 7 other resident blocks (TLP, not pipelining).
// STATIC-SHIFT softmax: Q pre-scaled to log2 domain; p=exp2(s) directly
// (shift-invariance, no overflow for normalized inputs); l lane-partial.
// ---------------------------------------------------------------------------
__global__ __launch_bounds__(256, 8) void attn_mfma(const short* __restrict__ qkv,
                                                    const short* __restrict__ vT,
                                                    const unsigned long long* __restrict__ kmask,
                                                    short* __restrict__ y) {
  __shared__ __align__(16) char Ks[8192];   // [key][128B], swizzled
  __shared__ __align__(16) char Vs[8192];   // [d][128B perm-keys], swizzled
  __shared__ unsigned long long km[32];
  const int tid = threadIdx.x, lane = tid & 63;
  const int w = tid >> 6;                        // wave 0..3
  const int g = lane >> 4, cw = lane & 15;

  // long-first mapping: qt descends with block id; bh stripes the 8 XCDs
  const int qt = 31 - ((int)blockIdx.x >> 6);
  const int bh = blockIdx.x & 63;
  const int b = bh >> 4, h = bh & 15;

  const int xorm = (cw & 7) << 4;
  const int srow = w * 8 + (lane >> 3);                   // staging row (+u*32)
  const int scb = (((lane & 7) ^ ((lane >> 3) & 7)) << 4);

  if (tid < 32) km[tid] = kmask[b * 32 + tid];

  const char* ksrc = (const char*)qkv + ((size_t)(b * TT + srow) * C3 + CC + h * 64) * 2 + scb;
  const char* vsrc = (const char*)vT + ((size_t)(bh * 64 + srow) * TT) * 2 + scb;

  // hoisted LDS read offsets (loop-invariant)
  const int kro = cw * 128;
  const int sz0 = (g * 16) ^ xorm;
  const int sz1 = (64 + g * 16) ^ xorm;

  const int qw = qt * 64 + w * 16;

  // Q fragments (B-operand; Q pre-scaled by log2(e)/8)
  short8 qf[2];
#pragma unroll
  for (int ks = 0; ks < 2; ++ks)
    qf[ks] = *reinterpret_cast<const short8*>(
        &qkv[(size_t)(b * TT + qw + cw) * C3 + h * 64 + ks * 32 + g * 8]);

  f32x4 o[4];
#pragma unroll
  for (int nd = 0; nd < 4; ++nd) o[nd] = (f32x4){0.f, 0.f, 0.f, 0.f};
  float ls = 0.f;

  const int niter = qt + 1;
#pragma unroll 1
  for (int t = 0; t < niter; ++t) {
    __syncthreads();   // previous tile's LDS reads done (t=0: km store visible)
#pragma unroll
    for (int u = 0; u < 2; ++u) {
      gload16(ksrc + (size_t)(t * 64) * (C3 * 2) + (size_t)(u * 32) * (C3 * 2),
              Ks + u * 4096 + tid * 16);
      gload16(vsrc + (size_t)(u * 32) * (TT * 2) + (size_t)t * 128,
              Vs + u * 4096 + tid * 16);
    }
    __syncthreads();   // staging drained + visible

    // ---- S^T = K Q^T : lane holds q = cw, keys nt*16 + g*4 + j ----
    f32x4 s[4];
    __builtin_amdgcn_s_setprio(1);
#pragma unroll
    for (int nt = 0; nt < 4; ++nt) {
      short8 kf0 = *reinterpret_cast<const short8*>(Ks + nt * 2048 + kro + sz0);
      short8 kf1 = *reinterpret_cast<const short8*>(Ks + nt * 2048 + kro + sz1);
      f32x4 z = (f32x4){0.f, 0.f, 0.f, 0.f};
      s[nt] = __builtin_amdgcn_mfma_f32_16x16x32_bf16(kf0, qf[0], z, 0, 0, 0);
      s[nt] = __builtin_amdgcn_mfma_f32_16x16x32_bf16(kf1, qf[1], s[nt], 0, 0, 0);
    }
    __builtin_amdgcn_s_setprio(0);

    // ---- mask (diagonal / padded tiles only); s in log2 domain ----
    const int kbase = t * 64;
    const unsigned long long kb = km[t];
    if ((kbase + 63 > qw) || (kb != ~0ULL)) {
      const int q = qw + cw;
#pragma unroll
      for (int nt = 0; nt < 4; ++nt)
#pragma unroll
        for (int j = 0; j < 4; ++j) {
          const int kh = nt * 16 + g * 4 + j;
          const bool mok = (kb >> kh) & 1;
          if (!(mok && kbase + kh <= q)) s[nt][j] = -1e30f;
        }
    }

    // ---- static-shift softmax: p = exp2(s), lane-partial l ----
    float rs = 0.f;
#pragma unroll
    for (int nt = 0; nt < 4; ++nt)
#pragma unroll
      for (int j = 0; j < 4; ++j) {
        const float p = exp2a(s[nt][j]);
        s[nt][j] = p;
        rs += p;
      }
    ls += rs;

    // ---- pack P into PV A-frags ----
    short8 pa[2];
#pragma unroll
    for (int ks2 = 0; ks2 < 2; ++ks2) {
      union { unsigned u[4]; short8 s8; } pc;
      pc.u[0] = cvtpk(s[2 * ks2][0], s[2 * ks2][1]);
      pc.u[1] = cvtpk(s[2 * ks2][2], s[2 * ks2][3]);
      pc.u[2] = cvtpk(s[2 * ks2 + 1][0], s[2 * ks2 + 1][1]);
      pc.u[3] = cvtpk(s[2 * ks2 + 1][2], s[2 * ks2 + 1][3]);
      pa[ks2] = pc.s8;
    }

    // ---- O += P V ----
    __builtin_amdgcn_s_setprio(1);
#pragma unroll
    for (int ks2 = 0; ks2 < 2; ++ks2)
#pragma unroll
      for (int nd = 0; nd < 4; ++nd) {
        short8 vf = *reinterpret_cast<const short8*>(
            Vs + nd * 2048 + kro + (ks2 ? sz1 : sz0));
        o[nd] = __builtin_amdgcn_mfma_f32_16x16x32_bf16(pa[ks2], vf, o[nd], 0, 0, 0);
      }
    __builtin_amdgcn_s_setprio(0);
  }

  // ---- epilogue: reduce l across the 4 row-owner lanes, y = O / l ----
  ls += __shfl_xor(ls, 16);
  ls += __shfl_xor(ls, 32);
#pragma unroll
  for (int j = 0; j < 4; ++j) {
    const float lj = __shfl(ls, (lane & 48) | (g * 4 + j));
    const float inv = 1.f / lj;
    const int q = qw + g * 4 + j;
#pragma unroll
    for (int nd = 0; nd < 4; ++nd)
      y[(size_t)(b * TT + q) * CC + h * 64 + nd * 16 + cw] = bf16b(o[nd][j] * inv);
  }
}

// ---------------------------------------------------------------------------
extern "C" void kernel_launch(void* const* d_in, const int* in_sizes, int n_in,
                              void* d_out, int out_size, void* d_ws, size_t ws_size,
                              hipStream_t stream) {
  const float* x      = (const float*)d_in[0];
  const int*   amask  = (const int*)d_in[1];
  const float* W_attn = (const float*)d_in[2];
  const float* W_proj = (const float*)d_in[3];

  char* ws = (char*)d_ws;
  short* xb  = (short*)(ws);                    // [8192][1024] bf16   16.8 MB
  short* Wta = (short*)(ws + 16777216);         // [3072][1024] bf16    6.3 MB
  short* Wtp = (short*)(ws + 23068672);         // [1024][1024] bf16    2.1 MB
  short* qkv = (short*)(ws + 25165824);         // [8192][3072] bf16   50.3 MB (V third unused)
  short* y   = (short*)(ws + 75497472);         // [8192][1024] bf16   16.8 MB
  short* vT  = (short*)(ws + 92274688);         // [64bh][64d][2048t]  16.8 MB
  unsigned long long* kmask = (unsigned long long*)(ws + 109051904);  // 128 u64

  const float SC = 0.18033688011112043f;        // log2(e)/8

  prep<<<8224, 256, 0, stream>>>(x, xb, W_attn, Wta, W_proj, Wtp, amask, kmask, SC);
  {
    dim3 g(C3 / 128, MM / 128);
    gemm_bt<2><<<g, 256, 0, stream>>>(xb, Wta, qkv, vT, MM, C3, CC);
  }
  attn_mfma<<<2048, 256, 0, stream>>>(qkv, vT, kmask, y);
  {
    dim3 g(CC / 128, MM / 128);
    gemm_bt<0><<<g, 256, 0, stream>>>(y, Wtp, (void*)d_out, nullptr, MM, CC, CC);
  }
}

// Round 14
// 153.327 us; speedup vs baseline: 1.1139x; 1.1139x over previous
//
#include <hip/hip_runtime.h>
#include <hip/hip_bf16.h>
#include <math.h>

#define TT 2048
#define CC 1024
#define C3 3072
#define MM 8192   // B*T

typedef __attribute__((ext_vector_type(8))) short short8;
typedef __attribute__((ext_vector_type(4))) float f32x4;

__device__ __forceinline__ short bf16b(float x) {
  __hip_bfloat16 h = __float2bfloat16(x);
  return *reinterpret_cast<short*>(&h);
}

__device__ __forceinline__ unsigned cvtpk(float lo, float hi) {
  unsigned r;
  asm("v_cvt_pk_bf16_f32 %0, %1, %2" : "=v"(r) : "v"(lo), "v"(hi));
  return r;
}

__device__ __forceinline__ float exp2a(float x) {
  float r;
  asm("v_exp_f32 %0, %1" : "=v"(r) : "v"(x));
  return r;
}

__device__ __forceinline__ void gload16(const void* g, void* l) {
  __builtin_amdgcn_global_load_lds(
      (const __attribute__((address_space(1))) unsigned int*)g,
      (__attribute__((address_space(3))) unsigned int*)l, 16, 0, 0);
}

// ---------------------------------------------------------------------------
// Fused prep: [0,4096) x->bf16; [4096,7168) W_attn^T (Q cols scaled);
// [7168,8192) W_proj^T; [8192,8224) amask->bitmask.  One launch, 4 jobs.
// ---------------------------------------------------------------------------
__device__ __forceinline__ void cvt_t_body(const float* __restrict__ in,
                                           short* __restrict__ out, int R, int Cc,
                                           int c0, int r0, int limit, float scale,
                                           float (*t)[33], int tid) {
  const int tx = tid & 31, ty = tid >> 5;
#pragma unroll
  for (int i = 0; i < 4; ++i)
    t[ty + i * 8][tx] = in[(size_t)(r0 + ty + i * 8) * Cc + c0 + tx];
  __syncthreads();
#pragma unroll
  for (int i = 0; i < 4; ++i) {
    const int orow = c0 + ty + i * 8;
    const float f = (orow < limit) ? scale : 1.f;
    out[(size_t)orow * R + r0 + tx] = bf16b(t[tx][ty + i * 8] * f);
  }
}

__global__ __launch_bounds__(256) void prep(const float* __restrict__ x,
                                            short* __restrict__ xb,
                                            const float* __restrict__ Wa,
                                            short* __restrict__ Wta,
                                            const float* __restrict__ Wp,
                                            short* __restrict__ Wtp,
                                            const int* __restrict__ amask,
                                            unsigned long long* __restrict__ kmask,
                                            float scaleQ) {
  __shared__ float t[32][33];
  const int bid = blockIdx.x, tid = threadIdx.x;
  if (bid < 4096) {
    const int i = (bid * 256 + tid) * 8;
    float4 a = *reinterpret_cast<const float4*>(x + i);
    float4 b = *reinterpret_cast<const float4*>(x + i + 4);
    short8 r;
    r[0] = bf16b(a.x); r[1] = bf16b(a.y); r[2] = bf16b(a.z); r[3] = bf16b(a.w);
    r[4] = bf16b(b.x); r[5] = bf16b(b.y); r[6] = bf16b(b.z); r[7] = bf16b(b.w);
    *reinterpret_cast<short8*>(xb + i) = r;
  } else if (bid < 7168) {
    const int lb = bid - 4096;
    cvt_t_body(Wa, Wta, CC, C3, (lb % 96) * 32, (lb / 96) * 32, CC, scaleQ, t, tid);
  } else if (bid < 8192) {
    const int lb = bid - 7168;
    cvt_t_body(Wp, Wtp, CC, CC, (lb & 31) * 32, (lb >> 5) * 32, 0, 1.f, t, tid);
  } else {
    const int gw = (bid - 8192) * 4 + (tid >> 6);
    unsigned long long bits = __ballot(amask[gw * 64 + (tid & 63)] != 0);
    if ((tid & 63) == 0) kmask[gw] = bits;
  }
}

// ---------------------------------------------------------------------------
// bf16 MFMA GEMM: C[M,N] = A[M,K] * Bt[N,K]^T.  128x128 tile, BK=64 (128B
// LDS rows, slot^=(row&7) swizzle: measured 0 bank conflicts), 256 threads =
// 4 waves (2x2), 4x4 16x16 frags/wave, 32 MFMA/iter.  2-deep counted-vmcnt
// pipeline (2 x 32KB bufs).  Natural block order (bx%8 XCD striping).
// MODE 0: fp32 out.  MODE 2 (qkv): cols<2048 -> bf16 qkv; cols>=2048 (V) ->
// LDS-transpose epilogue -> key-permuted vT[bh*64+d][t] (packed b64 writes).
// ---------------------------------------------------------------------------
template <int MODE>
__global__ __launch_bounds__(256) void gemm_bt(const short* __restrict__ A,
                                               const short* __restrict__ Bt,
                                               void* __restrict__ Cout,
                                               short* __restrict__ vT,
                                               int M, int N, int K) {
  __shared__ __align__(16) char Ls[2 * 32768];   // [buf][A 16KB | B 16KB]
  const int tid = threadIdx.x, lane = tid & 63, w = tid >> 6;
  const int g = lane >> 4, cw = lane & 15;
  const int m0 = blockIdx.y * 128, n0 = blockIdx.x * 128;
  const int wr = (w >> 1) * 64, wc = (w & 1) * 64;

  f32x4 acc[4][4];
#pragma unroll
  for (int i = 0; i < 4; ++i)
#pragma unroll
    for (int j = 0; j < 4; ++j) acc[i][j] = (f32x4){0.f, 0.f, 0.f, 0.f};

  // staging: row r = u*32 + (tid>>3), physical 16B slot tid&7 holds
  // logical k-group (tid&7) ^ (r&7)  (pre-swizzled source)
  const int sr = tid >> 3;                              // 0..31 (+u*32)
  const int sc = ((tid & 7) ^ (sr & 7)) << 3;           // source k elements
  const short* Asrc = A + (size_t)(m0 + sr) * K + sc;
  const short* Bsrc = Bt + (size_t)(n0 + sr) * K + sc;
  const size_t ustep = (size_t)32 * K;

  const int nt = K >> 6;   // BK=64; assumes nt >= 2

#define STAGE(kt, buf)                                                        \
  {                                                                           \
    char* dst_ = Ls + (buf) * 32768;                                          \
    const int k0_ = (kt) * 64;                                                \
    _Pragma("unroll")                                                         \
    for (int u = 0; u < 4; ++u)                                               \
      gload16(Asrc + u * ustep + k0_, dst_ + u * 4096 + tid * 16);            \
    _Pragma("unroll")                                                         \
    for (int u = 0; u < 4; ++u)                                               \
      gload16(Bsrc + u * ustep + k0_, dst_ + 16384 + u * 4096 + tid * 16);    \
  }

  STAGE(0, 0);
  STAGE(1, 1);

  const int xorm = (cw & 7) << 4;   // frag rows have row&7 == cw&7

#pragma unroll 1
  for (int t = 0; t < nt; ++t) {
    if (t + 1 < nt) {
      asm volatile("s_waitcnt vmcnt(8)" ::: "memory");
    } else {
      asm volatile("s_waitcnt vmcnt(0)" ::: "memory");
    }
    asm volatile("s_barrier" ::: "memory");

    const char* LA = Ls + (t & 1) * 32768;
    const char* LB = LA + 16384;

#pragma unroll
    for (int ks = 0; ks < 2; ++ks) {
      const int xo = (ks * 64 + g * 16) ^ xorm;
      short8 af[4], bf[4];
#pragma unroll
      for (int mt = 0; mt < 4; ++mt)
        af[mt] = *reinterpret_cast<const short8*>(LA + (wr + mt * 16 + cw) * 128 + xo);
#pragma unroll
      for (int ntn = 0; ntn < 4; ++ntn)
        bf[ntn] = *reinterpret_cast<const short8*>(LB + (wc + ntn * 16 + cw) * 128 + xo);
      __builtin_amdgcn_s_setprio(1);
#pragma unroll
      for (int mt = 0; mt < 4; ++mt)
#pragma unroll
        for (int ntn = 0; ntn < 4; ++ntn)
          acc[mt][ntn] = __builtin_amdgcn_mfma_f32_16x16x32_bf16(af[mt], bf[ntn], acc[mt][ntn], 0, 0, 0);
      __builtin_amdgcn_s_setprio(0);
    }

    asm volatile("s_barrier" ::: "memory");
    if (t + 2 < nt) STAGE(t + 2, t & 1);
  }
#undef STAGE

  if (MODE == 2 && n0 >= 2048) {
    // ---- fused V epilogue: acc -> LDS [d][t] (key-permuted, swizzled) ----
    char* Lt = Ls;   // 128 rows x 256B = 32KB
#pragma unroll
    for (int mt = 0; mt < 4; ++mt)
#pragma unroll
      for (int ntn = 0; ntn < 4; ++ntn) {
        const int dl = wc + ntn * 16 + cw;          // local d 0..127
        const int xm = (dl & 15) << 4;
        const int tl0 = wr + mt * 16 + g * 4;       // low 2 bits zero
        const int l5 = tl0 & 31;
        const int tp0 = (tl0 & ~31) | ((l5 & 8) << 1) | ((l5 & 4) << 1) |
                        ((l5 & 16) >> 2);           // + j passes through
        uint2 v;
        v.x = cvtpk(acc[mt][ntn][0], acc[mt][ntn][1]);
        v.y = cvtpk(acc[mt][ntn][2], acc[mt][ntn][3]);
        *reinterpret_cast<uint2*>(Lt + dl * 256 + ((tp0 * 2) ^ xm)) = v;
      }
    __syncthreads();
    // ---- coalesced write: lane pair covers one vT row (256B) ----
    const int dl = tid >> 1, hf = tid & 1;
    const int b = m0 >> 11, t0 = m0 & 2047;
    const int h = ((n0 - 2048) >> 6) + (dl >> 6);
    const int d = dl & 63;
    short* dst = vT + (size_t)((b * 16 + h) * 64 + d) * TT + t0 + hf * 64;
#pragma unroll
    for (int c = 0; c < 8; ++c) {
      const int ca = hf * 8 + c;
      const int slot = ca ^ (dl & 15);
      *reinterpret_cast<short8*>(dst + c * 8) =
          *reinterpret_cast<const short8*>(Lt + dl * 256 + slot * 16);
    }
    return;
  }

#pragma unroll
  for (int mt = 0; mt < 4; ++mt)
#pragma unroll
    for (int ntn = 0; ntn < 4; ++ntn)
#pragma unroll
      for (int j = 0; j < 4; ++j) {
        int row = m0 + wr + mt * 16 + g * 4 + j;
        int col = n0 + wc + ntn * 16 + cw;
        if (MODE == 2)
          ((short*)Cout)[(size_t)row * N + col] = bf16b(acc[mt][ntn][j]);
        else
          ((float*)Cout)[(size_t)row * N + col] = acc[mt][ntn][j];
      }
}

// ---------------------------------------------------------------------------
// Flash attention, swapped-operand MFMA.  Block = 4 waves (256 thr); wave
// owns 16 q rows; q-tile 64; KV-tile 64.  Causal pairing over 32 q-tiles:
// block handles {pr, 31-pr} (34 uniform iters).  Double-buffered staging
// with counted vmcnt(4) + raw s_barrier (r12 structure, measured best).
// STRIPED block mapping (bh = bid&63): co-resident blocks progress through
// the same qt schedule across bh -> near-ideal L2/L3 reuse (r13: FETCH
// 146->55 MB).  STATIC-SHIFT softmax (Q pre-scaled to log2 domain).
// ---------------------------------------------------------------------------
__global__ __launch_bounds__(256, 4) void attn_mfma(const short* __restrict__ qkv,
                                                    const short* __restrict__ vT,
                                                    const unsigned long long* __restrict__ kmask,
                                                    short* __restrict__ y) {
  __shared__ __align__(16) char Ks[2 * 8192];   // [buf][key][128B], swizzled
  __shared__ __align__(16) char Vs[2 * 8192];   // [buf][d][128B perm-keys], swizzled
  __shared__ unsigned long long km[32];
  const int tid = threadIdx.x, lane = tid & 63;
  const int w = tid >> 6;                        // wave 0..3
  const int g = lane >> 4, cw = lane & 15;

  // striped mapping: consecutive blocks span bh (same pr) -> shared qt timing
  const int bid = blockIdx.x;
  const int bh = bid & 63, pr = bid >> 6;
  const int b = bh >> 4, h = bh & 15;

  const int xorm = (cw & 7) << 4;
  const int srow = w * 8 + (lane >> 3);                   // staging row (+u*32)
  const int scb = (((lane & 7) ^ ((lane >> 3) & 7)) << 4);

  if (tid < 32) km[tid] = kmask[b * 32 + tid];

  const char* ksrc = (const char*)qkv + ((size_t)(b * TT + srow) * C3 + CC + h * 64) * 2 + scb;
  const char* vsrc = (const char*)vT + ((size_t)(bh * 64 + srow) * TT) * 2 + scb;

  // hoisted LDS read offsets (loop-invariant)
  const int kro = cw * 128;
  const int sz0 = (g * 16) ^ xorm;
  const int sz1 = (64 + g * 16) ^ xorm;

#pragma unroll 1
  for (int part = 0; part < 2; ++part) {
    const int qt = part ? 31 - pr : pr;
    const int qw = qt * 64 + w * 16;

    // Q fragments (B-operand; Q pre-scaled by log2(e)/8)
    short8 qf[2];
#pragma unroll
    for (int ks = 0; ks < 2; ++ks)
      qf[ks] = *reinterpret_cast<const short8*>(
          &qkv[(size_t)(b * TT + qw + cw) * C3 + h * 64 + ks * 32 + g * 8]);

    f32x4 o[4];
#pragma unroll
    for (int nd = 0; nd < 4; ++nd) o[nd] = (f32x4){0.f, 0.f, 0.f, 0.f};
    float ls = 0.f;

    const int niter = qt + 1;
    // prologue: stage tile 0 into buf 0
    const char* kp = ksrc;
    const char* vp = vsrc;
#pragma unroll
    for (int u = 0; u < 2; ++u) {
      gload16(kp + (size_t)(u * 32) * (C3 * 2), Ks + u * 4096 + tid * 16);
      gload16(vp + (size_t)(u * 32) * (TT * 2), Vs + u * 4096 + tid * 16);
    }

#pragma unroll 1
    for (int t = 0; t < niter; ++t) {
      const int cur = t & 1;
      if (t + 1 < niter) {
        kp += (size_t)64 * (C3 * 2);
        vp += 128;
        char* dK = Ks + (cur ^ 1) * 8192;
        char* dV = Vs + (cur ^ 1) * 8192;
#pragma unroll
        for (int u = 0; u < 2; ++u) {
          gload16(kp + (size_t)(u * 32) * (C3 * 2), dK + u * 4096 + tid * 16);
          gload16(vp + (size_t)(u * 32) * (TT * 2), dV + u * 4096 + tid * 16);
        }
        asm volatile("s_waitcnt vmcnt(4)" ::: "memory");
      } else {
        asm volatile("s_waitcnt vmcnt(0)" ::: "memory");
      }
      asm volatile("s_barrier" ::: "memory");

      const int kbase = t * 64;
      if (kbase <= qw + 15) {
        const char* KB = Ks + cur * 8192;
        const char* VB = Vs + cur * 8192;

        // ---- S^T = K Q^T : lane holds q = cw, keys nt*16 + g*4 + j ----
        f32x4 s[4];
        __builtin_amdgcn_s_setprio(1);
#pragma unroll
        for (int nt = 0; nt < 4; ++nt) {
          short8 kf0 = *reinterpret_cast<const short8*>(KB + nt * 2048 + kro + sz0);
          short8 kf1 = *reinterpret_cast<const short8*>(KB + nt * 2048 + kro + sz1);
          f32x4 z = (f32x4){0.f, 0.f, 0.f, 0.f};
          s[nt] = __builtin_amdgcn_mfma_f32_16x16x32_bf16(kf0, qf[0], z, 0, 0, 0);
          s[nt] = __builtin_amdgcn_mfma_f32_16x16x32_bf16(kf1, qf[1], s[nt], 0, 0, 0);
        }
        __builtin_amdgcn_s_setprio(0);

        // ---- mask (diagonal / padded tiles only); s in log2 domain ----
        const unsigned long long kb = km[t];
        if ((kbase + 63 > qw) || (kb != ~0ULL)) {
          const int q = qw + cw;
#pragma unroll
          for (int nt = 0; nt < 4; ++nt)
#pragma unroll
            for (int j = 0; j < 4; ++j) {
              const int kh = nt * 16 + g * 4 + j;
              const bool mok = (kb >> kh) & 1;
              if (!(mok && kbase + kh <= q)) s[nt][j] = -1e30f;
            }
        }

        // ---- static-shift softmax: p = exp2(s), lane-partial l ----
        float rs = 0.f;
#pragma unroll
        for (int nt = 0; nt < 4; ++nt)
#pragma unroll
          for (int j = 0; j < 4; ++j) {
            const float p = exp2a(s[nt][j]);
            s[nt][j] = p;
            rs += p;
          }
        ls += rs;

        // ---- pack P into PV A-frags ----
        short8 pa[2];
#pragma unroll
        for (int ks2 = 0; ks2 < 2; ++ks2) {
          union { unsigned u[4]; short8 s8; } pc;
          pc.u[0] = cvtpk(s[2 * ks2][0], s[2 * ks2][1]);
          pc.u[1] = cvtpk(s[2 * ks2][2], s[2 * ks2][3]);
          pc.u[2] = cvtpk(s[2 * ks2 + 1][0], s[2 * ks2 + 1][1]);
          pc.u[3] = cvtpk(s[2 * ks2 + 1][2], s[2 * ks2 + 1][3]);
          pa[ks2] = pc.s8;
        }

        // ---- O += P V ----
        __builtin_amdgcn_s_setprio(1);
#pragma unroll
        for (int ks2 = 0; ks2 < 2; ++ks2)
#pragma unroll
          for (int nd = 0; nd < 4; ++nd) {
            short8 vf = *reinterpret_cast<const short8*>(
                VB + nd * 2048 + kro + (ks2 ? sz1 : sz0));
            o[nd] = __builtin_amdgcn_mfma_f32_16x16x32_bf16(pa[ks2], vf, o[nd], 0, 0, 0);
          }
        __builtin_amdgcn_s_setprio(0);
      }
      asm volatile("s_barrier" ::: "memory");
    }

    // ---- epilogue: reduce l across the 4 row-owner lanes, y = O / l ----
    ls += __shfl_xor(ls, 16);
    ls += __shfl_xor(ls, 32);
#pragma unroll
    for (int j = 0; j < 4; ++j) {
      const float lj = __shfl(ls, (lane & 48) | (g * 4 + j));
      const float inv = 1.f / lj;
      const int q = qw + g * 4 + j;
#pragma unroll
      for (int nd = 0; nd < 4; ++nd)
        y[(size_t)(b * TT + q) * CC + h * 64 + nd * 16 + cw] = bf16b(o[nd][j] * inv);
    }
  }
}

// ---------------------------------------------------------------------------
extern "C" void kernel_launch(void* const* d_in, const int* in_sizes, int n_in,
                              void* d_out, int out_size, void* d_ws, size_t ws_size,
                              hipStream_t stream) {
  const float* x      = (const float*)d_in[0];
  const int*   amask  = (const int*)d_in[1];
  const float* W_attn = (const float*)d_in[2];
  const float* W_proj = (const float*)d_in[3];

  char* ws = (char*)d_ws;
  short* xb  = (short*)(ws);                    // [8192][1024] bf16   16.8 MB
  short* Wta = (short*)(ws + 16777216);         // [3072][1024] bf16    6.3 MB
  short* Wtp = (short*)(ws + 23068672);         // [1024][1024] bf16    2.1 MB
  short* qkv = (short*)(ws + 25165824);         // [8192][3072] bf16   50.3 MB (V third unused)
  short* y   = (short*)(ws + 75497472);         // [8192][1024] bf16   16.8 MB
  short* vT  = (short*)(ws + 92274688);         // [64bh][64d][2048t]  16.8 MB
  unsigned long long* kmask = (unsigned long long*)(ws + 109051904);  // 128 u64

  const float SC = 0.18033688011112043f;        // log2(e)/8

  prep<<<8224, 256, 0, stream>>>(x, xb, W_attn, Wta, W_proj, Wtp, amask, kmask, SC);
  {
    dim3 g(C3 / 128, MM / 128);
    gemm_bt<2><<<g, 256, 0, stream>>>(xb, Wta, qkv, vT, MM, C3, CC);
  }
  attn_mfma<<<1024, 256, 0, stream>>>(qkv, vT, kmask, y);
  {
    dim3 g(CC / 128, MM / 128);
    gemm_bt<0><<<g, 256, 0, stream>>>(y, Wtp, (void*)d_out, nullptr, MM, CC, CC);
  }
}